// Round 15
// baseline (414.604 us; speedup 1.0000x reference)
//
#include <hip/hip_runtime.h>
#include <stdint.h>

// ---- problem constants ----
#define NPATCH 3136      // 64 images * 49 patches
#define MPAD   3328      // 13 * 256 (= 208 * 16)
#define NBANK  100000
#define NBPAD  100096    // 6256 * 16 = 391 * 256
#define DIM    768
#define BM 256
#define BN 256
#define BK 64               // K-tile
#define KTILES (DIM / BK)   // 12
#define MT 13               // MPAD / BM
#define NT 391              // NBPAD / BN
#define NRG    (MPAD / 16)   // 208 A row-groups
#define NBRG   (NBPAD / 16)  // 6256 B row-groups
#define NCHUNK (KTILES * NRG * 64)   // 159744 16B chunks in Af

typedef __attribute__((ext_vector_type(4))) float f32x4;
typedef __attribute__((ext_vector_type(4))) int   i32x4;

// monotonic float<->uint mapping for atomicMax on floats (incl. negatives)
__device__ __forceinline__ unsigned fkey(float f) {
    unsigned u = __float_as_uint(f);
    return (u & 0x80000000u) ? ~u : (u | 0x80000000u);
}
__device__ __forceinline__ float funkey(unsigned u) {
    return __uint_as_float((u & 0x80000000u) ? (u ^ 0x80000000u) : ~u);
}

// ---- kernel 0: zero the per-patch max-key buffer ----
__global__ void k_init(unsigned* __restrict__ keys) {
    int i = blockIdx.x * 256 + threadIdx.x;
    if (i < MPAD) keys[i] = 0u;
}

// ---- shared: quantize one 768-float row to int8 with scale sa = vmax/(127*(||a||+eps))
// dst may be global or LDS (generic address space).
__device__ __forceinline__ void quant_row(const float* __restrict__ src,
                                          signed char* __restrict__ dst,
                                          float* __restrict__ sa_p, int lane) {
    f32x4 v[3];
    float ss = 0.f, vm = 0.f;
#pragma unroll
    for (int i = 0; i < 3; i++) {
        v[i] = ((const f32x4*)src)[lane + 64 * i];
#pragma unroll
        for (int c = 0; c < 4; c++) {
            ss += v[i][c] * v[i][c];
            vm = fmaxf(vm, fabsf(v[i][c]));
        }
    }
#pragma unroll
    for (int d = 1; d < 64; d <<= 1) {
        ss += __shfl_xor(ss, d);
        vm = fmaxf(vm, __shfl_xor(vm, d));
    }
    float k = (vm > 0.f) ? 127.0f / vm : 0.f;
#pragma unroll
    for (int i = 0; i < 3; i++) {
        char4 o;
        o.x = (signed char)__float2int_rn(v[i][0] * k);
        o.y = (signed char)__float2int_rn(v[i][1] * k);
        o.z = (signed char)__float2int_rn(v[i][2] * k);
        o.w = (signed char)__float2int_rn(v[i][3] * k);
        ((char4*)dst)[lane + 64 * i] = o;
    }
    if (lane == 0) *sa_p = vm / (127.0f * (sqrtf(ss) + 1e-12f));
}

__device__ __forceinline__ void zero_row(signed char* __restrict__ dst,
                                         float* __restrict__ sa_p, int lane) {
    char4 z; z.x = z.y = z.z = z.w = 0;
#pragma unroll
    for (int i = 0; i < 3; i++) ((char4*)dst)[lane + 64 * i] = z;
    if (lane == 0) *sa_p = 0.f;
}

// ---- kernel 1: patches (drop CLS) -> int8 Aq[MPAD][DIM] + sa[MPAD] ----
__global__ void k_q8a(const float* __restrict__ tokens, signed char* __restrict__ A,
                      float* __restrict__ sa) {
    int wv = threadIdx.x >> 6, lane = threadIdx.x & 63;
    int r = blockIdx.x * 4 + wv;
    if (r >= MPAD) return;
    signed char* dst = A + (size_t)r * DIM;
    if (r >= NPATCH) { zero_row(dst, sa + r, lane); return; }
    int b = r / 49, j = r % 49;
    const float* src = tokens + (size_t)(b * 50 + 1 + j) * DIM;  // skip CLS
    quant_row(src, dst, sa + r, lane);
}

// ---- kernel 1b: repack Aq row-major -> Af fragment-major (R9-proven).
// Af chunk d = ((kt*NRG + rg)*64 + khi*16 + lr) holds Aq[rg*16+lr][kt*64+khi*16 .. +16).
__global__ void k_rep(const signed char* __restrict__ Aq, signed char* __restrict__ Af) {
    int d = blockIdx.x * 256 + threadIdx.x;
    if (d >= NCHUNK) return;
    int l6 = d & 63;
    int rg = (d >> 6) % NRG;
    int kt = d / (NRG * 64);
    int row = rg * 16 + (l6 & 15);
    int kc  = kt * 64 + (l6 >> 4) * 16;
    *(i32x4*)(Af + (size_t)d * 16) = *(const i32x4*)(Aq + (size_t)row * DIM + kc);
}

// ---- kernel 2: bank -> int8 fragment-major Bf + sb, fused quant+transpose.
// One block per 16-row group: quant rows into LDS (padded stride), then write out
// 12 kt-chunks of 1 KB each, fully coalesced. Bf mirrors Af with NBRG groups.
__global__ void __launch_bounds__(256) k_q8b(const float* __restrict__ mb,
                                             signed char* __restrict__ Bf,
                                             float* __restrict__ sb) {
    __shared__ __align__(16) signed char sm[16][784];   // 784 = 768+16 (bank-spread pad)
    int rg = blockIdx.x;                                 // 0..NBRG-1
    int wv = threadIdx.x >> 6, lane = threadIdx.x & 63;
#pragma unroll
    for (int j = 0; j < 4; j++) {
        int ri = wv * 4 + j;
        int row = rg * 16 + ri;
        if (row < NBANK) quant_row(mb + (size_t)row * DIM, &sm[ri][0], sb + row, lane);
        else             zero_row(&sm[ri][0], sb + row, lane);
    }
    __syncthreads();
    int t = threadIdx.x;
#pragma unroll
    for (int i = 0; i < 3; i++) {
        int idx = i * 256 + t;          // 0..767 = kt(12) * 64 lane-chunks
        int kt = idx >> 6, l6 = idx & 63;
        i32x4 v = *(const i32x4*)(&sm[l6 & 15][kt * 64 + (l6 >> 4) * 16]);
        *(i32x4*)(Bf + (((size_t)kt * NBRG + rg) * 64 + l6) * 16) = v;
    }
}

// ---- kernel 3: int8 MFMA GEMM (16x16x64), NO LDS / NO barriers (R11/R14 line).
// R14 confirmed the per-CU VMEM byte-rate wall (~36 B/cyc): MfmaUtil scaled
// exactly with bytes/MAC. Continue: per-wave tile 128x128 (8m x 8n frags),
// bytes/MAC 0.0229 -> 0.0153. acc 256 (AGPR) + operand dbuf 128 -> 1 wave/SIMD.
// Latency coverage stays ~1306 cyc MFMA per prefetch (>> L2/L3 latency).
__global__ void __launch_bounds__(256, 1) k_gemm(const signed char* __restrict__ Af,
                                                 const signed char* __restrict__ Bf,
                                                 const float* __restrict__ sb,
                                                 unsigned* __restrict__ keys) {
    // T1: bijective XCD swizzle (m204; nwg=5083, nwg%8=3)
    const int nwg = MT * NT;
    const int q = nwg >> 3, r8 = nwg & 7;
    const int xcd = blockIdx.x & 7, loc = blockIdx.x >> 3;
    const int wg = (xcd < r8 ? xcd * (q + 1) : r8 * (q + 1) + (xcd - r8) * q) + loc;
    const int mt = wg % MT;          // m-fastest within an XCD: 13 blocks share one B panel
    const int nt = wg / MT;

    const int t = threadIdx.x;
    const int lane = t & 63, wv = t >> 6;
    const int lr = lane & 15;
    const int khi = lane >> 4;         // 0..3 -> 16 B k-chunk of the 64-elem k

    const int wm = (wv >> 1) * 128;    // 0 or 128
    const int wn = (wv & 1) * 128;     // 0 or 128

    const int rg0 = mt * (BM / 16) + (wm >> 4);
    const int cg0 = nt * (BN / 16) + (wn >> 4);
    const signed char* Afw = Af + ((size_t)rg0 * 64 + (khi * 16 + lr)) * 16;
    const signed char* Bfw = Bf + ((size_t)cg0 * 64 + (khi * 16 + lr)) * 16;

    auto loadA = [&](i32x4* a, int kt) {
#pragma unroll
        for (int mi = 0; mi < 8; mi++)
            a[mi] = *(const i32x4*)(Afw + (((size_t)kt * NRG + mi) << 10));
    };
    auto loadB = [&](i32x4* b, int kt) {
#pragma unroll
        for (int ni = 0; ni < 8; ni++)
            b[ni] = *(const i32x4*)(Bfw + (((size_t)kt * NBRG + ni) << 10));
    };

    i32x4 acc[8][8] = {};
    i32x4 aA[8], bA[8], aB[8], bB[8];
    loadA(aA, 0); loadB(bA, 0);
#pragma unroll
    for (int tt = 0; tt < KTILES; tt++) {
        if (tt + 1 < KTILES) {                       // depth-1 register prefetch
            loadA((tt & 1) ? aA : aB, tt + 1);
            loadB((tt & 1) ? bA : bB, tt + 1);
        }
        const i32x4* av = (tt & 1) ? aB : aA;
        const i32x4* bv = (tt & 1) ? bB : bA;
        __builtin_amdgcn_s_setprio(1);
#pragma unroll
        for (int mi = 0; mi < 8; mi++)
#pragma unroll
            for (int ni = 0; ni < 8; ni++)
                acc[mi][ni] = __builtin_amdgcn_mfma_i32_16x16x64_i8(
                    av[mi], bv[ni], acc[mi][ni], 0, 0, 0);
        __builtin_amdgcn_s_setprio(0);
    }

    // epilogue: m = max over this block's cols of sb[col]*dot; atomicMax per row.
    // sa[row] is a positive per-row constant -> applied in k_final (max commutes).
    const int rowbase = mt * BM + wm;
    const int colbase = nt * BN + wn;
    float sbv[8];
    bool cok[8];
#pragma unroll
    for (int ni = 0; ni < 8; ni++) {
        int col = colbase + ni * 16 + lr;
        cok[ni] = (col < NBANK);
        sbv[ni] = sb[col];
    }
#pragma unroll
    for (int mi = 0; mi < 8; mi++) {
#pragma unroll
        for (int j = 0; j < 4; j++) {
            float m = -3.4e38f;
#pragma unroll
            for (int ni = 0; ni < 8; ni++)
                if (cok[ni]) m = fmaxf(m, sbv[ni] * (float)acc[mi][ni][j]);
#pragma unroll
            for (int d = 1; d < 16; d <<= 1)   // reduce 16 lanes sharing a C-row
                m = fmaxf(m, __shfl_xor(m, d));
            if (lr == 0) {
                int row = rowbase + mi * 16 + khi * 4 + j;
                if (row < NPATCH) atomicMax(&keys[row], fkey(m));
            }
        }
    }
}

// ---- kernel 4: scores[b] = max_j sqrt(max(2 - 2*sa*keymax, 1e-12)) ----
__global__ void k_final(const unsigned* __restrict__ keys, const float* __restrict__ sa,
                        float* __restrict__ out) {
    int b = threadIdx.x;
    if (b >= 64) return;
    float best = 0.f;
    for (int j = 0; j < 49; j++) {
        int row = b * 49 + j;
        float c = sa[row] * funkey(keys[row]);
        float d2 = fmaxf(2.0f - 2.0f * c, 1e-12f);
        best = fmaxf(best, sqrtf(d2));
    }
    out[b] = best;
}

extern "C" void kernel_launch(void* const* d_in, const int* in_sizes, int n_in,
                              void* d_out, int out_size, void* d_ws, size_t ws_size,
                              hipStream_t stream) {
    const float* tokens = (const float*)d_in[0];   // [64, 50, 768] f32
    const float* mb     = (const float*)d_in[1];   // [100000, 768] f32
    float* out = (float*)d_out;                    // [64] f32

    // ws layout (16B-aligned regions):
    //   Aq i8 [MPAD*DIM] | Af i8 [NCHUNK*16] | Bf i8 [KTILES*NBRG*64*16]
    //   | sa f32[MPAD] | sb f32[NBPAD] | keys u32[MPAD]
    char* ws = (char*)d_ws;
    signed char* Aq = (signed char*)ws;
    signed char* Af = (signed char*)(ws + (size_t)MPAD * DIM);
    signed char* Bf = (signed char*)(ws + (size_t)MPAD * DIM + (size_t)NCHUNK * 16);
    float* sa       = (float*)(ws + (size_t)MPAD * DIM + (size_t)NCHUNK * 16
                                  + (size_t)KTILES * NBRG * 64 * 16);
    float* sb       = sa + MPAD;
    unsigned* keys  = (unsigned*)(sb + NBPAD);

    k_init <<<(MPAD + 255) / 256, 256, 0, stream>>>(keys);
    k_q8a  <<<MPAD / 4, 256, 0, stream>>>(tokens, Aq, sa);
    k_rep  <<<(NCHUNK + 255) / 256, 256, 0, stream>>>(Aq, Af);
    k_q8b  <<<NBRG, 256, 0, stream>>>(mb, Bf, sb);
    k_gemm <<<MT * NT, 256, 0, stream>>>(Af, Bf, sb, keys);
    k_final<<<1, 64, 0, stream>>>(keys, sa, out);
}

// Round 16
// 347.872 us; speedup vs baseline: 1.1918x; 1.1918x over previous
//
#include <hip/hip_runtime.h>
#include <stdint.h>

// ---- problem constants ----
#define NPATCH 3136      // 64 images * 49 patches
#define MPAD   3328      // 26 * 128 (= 208 * 16)
#define NBANK  100000
#define NBPAD  100096    // 6256 * 16 = 391 * 256
#define DIM    768
#define BM 128
#define BN 256
#define BK 64               // K-tile
#define KTILES (DIM / BK)   // 12
#define MT 26               // MPAD / BM
#define NT 391              // NBPAD / BN
#define NRG    (MPAD / 16)   // 208 A row-groups
#define NBRG   (NBPAD / 16)  // 6256 B row-groups
#define NCHUNK (KTILES * NRG * 64)   // 159744 16B chunks in Af
#define BPAN   (BN * BK)     // 16 KB B panel per K-tile

typedef __attribute__((ext_vector_type(4))) float f32x4;
typedef __attribute__((ext_vector_type(4))) int   i32x4;

// monotonic float<->uint mapping for atomicMax on floats (incl. negatives)
__device__ __forceinline__ unsigned fkey(float f) {
    unsigned u = __float_as_uint(f);
    return (u & 0x80000000u) ? ~u : (u | 0x80000000u);
}
__device__ __forceinline__ float funkey(unsigned u) {
    return __uint_as_float((u & 0x80000000u) ? (u ^ 0x80000000u) : ~u);
}

// ---- kernel 0: zero the per-patch max-key buffer ----
__global__ void k_init(unsigned* __restrict__ keys) {
    int i = blockIdx.x * 256 + threadIdx.x;
    if (i < MPAD) keys[i] = 0u;
}

// ---- shared: quantize one 768-float row to int8 with scale sa = vmax/(127*(||a||+eps))
// dst may be global or LDS (generic address space).
__device__ __forceinline__ void quant_row(const float* __restrict__ src,
                                          signed char* __restrict__ dst,
                                          float* __restrict__ sa_p, int lane) {
    f32x4 v[3];
    float ss = 0.f, vm = 0.f;
#pragma unroll
    for (int i = 0; i < 3; i++) {
        v[i] = ((const f32x4*)src)[lane + 64 * i];
#pragma unroll
        for (int c = 0; c < 4; c++) {
            ss += v[i][c] * v[i][c];
            vm = fmaxf(vm, fabsf(v[i][c]));
        }
    }
#pragma unroll
    for (int d = 1; d < 64; d <<= 1) {
        ss += __shfl_xor(ss, d);
        vm = fmaxf(vm, __shfl_xor(vm, d));
    }
    float k = (vm > 0.f) ? 127.0f / vm : 0.f;
#pragma unroll
    for (int i = 0; i < 3; i++) {
        char4 o;
        o.x = (signed char)__float2int_rn(v[i][0] * k);
        o.y = (signed char)__float2int_rn(v[i][1] * k);
        o.z = (signed char)__float2int_rn(v[i][2] * k);
        o.w = (signed char)__float2int_rn(v[i][3] * k);
        ((char4*)dst)[lane + 64 * i] = o;
    }
    if (lane == 0) *sa_p = vm / (127.0f * (sqrtf(ss) + 1e-12f));
}

__device__ __forceinline__ void zero_row(signed char* __restrict__ dst,
                                         float* __restrict__ sa_p, int lane) {
    char4 z; z.x = z.y = z.z = z.w = 0;
#pragma unroll
    for (int i = 0; i < 3; i++) ((char4*)dst)[lane + 64 * i] = z;
    if (lane == 0) *sa_p = 0.f;
}

// ---- kernel 1: patches (drop CLS) -> int8 Aq[MPAD][DIM] + sa[MPAD] ----
__global__ void k_q8a(const float* __restrict__ tokens, signed char* __restrict__ A,
                      float* __restrict__ sa) {
    int wv = threadIdx.x >> 6, lane = threadIdx.x & 63;
    int r = blockIdx.x * 4 + wv;
    if (r >= MPAD) return;
    signed char* dst = A + (size_t)r * DIM;
    if (r >= NPATCH) { zero_row(dst, sa + r, lane); return; }
    int b = r / 49, j = r % 49;
    const float* src = tokens + (size_t)(b * 50 + 1 + j) * DIM;  // skip CLS
    quant_row(src, dst, sa + r, lane);
}

// ---- kernel 1b: repack Aq row-major -> Af fragment-major (R9-proven).
// Af chunk d = ((kt*NRG + rg)*64 + khi*16 + lr) holds Aq[rg*16+lr][kt*64+khi*16 .. +16).
__global__ void k_rep(const signed char* __restrict__ Aq, signed char* __restrict__ Af) {
    int d = blockIdx.x * 256 + threadIdx.x;
    if (d >= NCHUNK) return;
    int l6 = d & 63;
    int rg = (d >> 6) % NRG;
    int kt = d / (NRG * 64);
    int row = rg * 16 + (l6 & 15);
    int kc  = kt * 64 + (l6 >> 4) * 16;
    *(i32x4*)(Af + (size_t)d * 16) = *(const i32x4*)(Aq + (size_t)row * DIM + kc);
}

// ---- kernel 2: bank -> int8 fragment-major Bf + sb, fused quant+transpose.
// One block per 16-row group: quant rows into LDS (padded stride), then write out
// 12 kt-chunks of 1 KB each, fully coalesced. Bf mirrors Af with NBRG groups.
__global__ void __launch_bounds__(256) k_q8b(const float* __restrict__ mb,
                                             signed char* __restrict__ Bf,
                                             float* __restrict__ sb) {
    __shared__ __align__(16) signed char sm[16][784];   // 784 = 768+16 (bank-spread pad)
    int rg = blockIdx.x;                                 // 0..NBRG-1
    int wv = threadIdx.x >> 6, lane = threadIdx.x & 63;
#pragma unroll
    for (int j = 0; j < 4; j++) {
        int ri = wv * 4 + j;
        int row = rg * 16 + ri;
        if (row < NBANK) quant_row(mb + (size_t)row * DIM, &sm[ri][0], sb + row, lane);
        else             zero_row(&sm[ri][0], sb + row, lane);
    }
    __syncthreads();
    int t = threadIdx.x;
#pragma unroll
    for (int i = 0; i < 3; i++) {
        int idx = i * 256 + t;          // 0..767 = kt(12) * 64 lane-chunks
        int kt = idx >> 6, l6 = idx & 63;
        i32x4 v = *(const i32x4*)(&sm[l6 & 15][kt * 64 + (l6 >> 4) * 16]);
        *(i32x4*)(Bf + (((size_t)kt * NBRG + rg) * 64 + l6) * 16) = v;
    }
}

// ---- kernel 3: int8 MFMA GEMM (16x16x64). R14 geometry (128x256 block,
// 4 waves of 64x128) + B via LDS DMA to cut TA bytes 33% (the measured
// ~36 B/cyc/CU vector-memory wall, confirmed R11->R14).
//  A: direct from global fragment-major, register double-buffered (R14).
//  B: block-shared 16KB panel per K-tile, global_load_lds (fragment-major ->
//     one contiguous linear copy, no swizzle), 3 rotating buffers,
//     R10-proven counted-vmcnt schedule: loadA(t+1) -> vmcnt(8) -> barrier ->
//     stageB(t+2) (post-barrier => race-free) -> compute(t).
//  FIFO/wave: sB(t)[4] lA(t)[4] sB(t+1)[4] lA(t+1)[4] |wait(8)| -> sB(t),lA(t) done.
__global__ void __launch_bounds__(256, 2) k_gemm(const signed char* __restrict__ Af,
                                                 const signed char* __restrict__ Bf,
                                                 const float* __restrict__ sb,
                                                 unsigned* __restrict__ keys) {
    __shared__ __align__(16) signed char Bl[3][BPAN];   // 48 KB

    // T1: bijective XCD swizzle (m204; nwg=10166, nwg%8=6)
    const int nwg = MT * NT;
    const int q = nwg >> 3, r8 = nwg & 7;
    const int xcd = blockIdx.x & 7, loc = blockIdx.x >> 3;
    const int wg = (xcd < r8 ? xcd * (q + 1) : r8 * (q + 1) + (xcd - r8) * q) + loc;
    const int mt = wg % MT;          // m-fastest within an XCD: 26 blocks share one B panel
    const int nt = wg / MT;

    const int t = threadIdx.x;
    const int lane = t & 63, wv = t >> 6;
    const int lr = lane & 15;
    const int khi = lane >> 4;         // 0..3 -> 16 B k-chunk of the 64-elem k

    const int wm = (wv >> 1) * 64;     // 0 or 64
    const int wn = (wv & 1) * 128;     // 0 or 128

    const int rg0 = mt * (BM / 16) + (wm >> 4);
    const int cg0 = nt * (BN / 16);
    const signed char* Afw = Af + ((size_t)rg0 * 64 + lane) * 16;

    // B panel staging: 1024 chunks of 16B, 4 per thread; Bf panel for (nt, kt) is
    // one contiguous 16 KB region -> linear copy, linear LDS dest.
    auto stageB = [&](signed char* Lb, int kt) {
        const signed char* src = Bf + (((size_t)kt * NBRG + cg0) << 10);
#pragma unroll
        for (int it = 0; it < 4; it++) {
            int id = it * 256 + t;
            __builtin_amdgcn_global_load_lds(
                (const __attribute__((address_space(1))) unsigned int*)(src + id * 16),
                (__attribute__((address_space(3))) unsigned int*)(Lb + id * 16), 16, 0, 0);
        }
    };

    auto loadA = [&](i32x4* a, int kt) {
#pragma unroll
        for (int mi = 0; mi < 4; mi++)
            a[mi] = *(const i32x4*)(Afw + (((size_t)kt * NRG + mi) << 10));
    };

    i32x4 acc[4][8] = {};
    const int bbase = (wv & 1) * 8192 + lane * 16;   // this wave's B half-panel + lane slot

    auto compute = [&](int buf, const i32x4* av) {
        const signed char* Bbuf = &Bl[buf][0];
        i32x4 bv[8];
#pragma unroll
        for (int ni = 0; ni < 8; ni++)
            bv[ni] = *(const i32x4*)(Bbuf + bbase + ni * 1024);   // linear ds_read_b128
        __builtin_amdgcn_s_setprio(1);
#pragma unroll
        for (int mi = 0; mi < 4; mi++)
#pragma unroll
            for (int ni = 0; ni < 8; ni++)
                acc[mi][ni] = __builtin_amdgcn_mfma_i32_16x16x64_i8(
                    av[mi], bv[ni], acc[mi][ni], 0, 0, 0);
        __builtin_amdgcn_s_setprio(0);
    };

    i32x4 aA[4], aB[4];
    // prologue FIFO: sB(0)[4], lA(0)[4], sB(1)[4]
    stageB(Bl[0], 0);
    loadA(aA, 0);
    stageB(Bl[1], 1);
#pragma unroll
    for (int tt = 0; tt < KTILES; tt++) {
        if (tt + 1 < KTILES) loadA((tt & 1) ? aA : aB, tt + 1);
        __builtin_amdgcn_sched_barrier(0);          // pin issue order (FIFO count depends on it)
        if (tt == KTILES - 1) asm volatile("s_waitcnt vmcnt(0)" ::: "memory");
        else                  asm volatile("s_waitcnt vmcnt(8)" ::: "memory");
        __builtin_amdgcn_s_barrier();               // all waves: buf tt%3 landed, prev reads done
        if (tt + 2 < KTILES) stageB(Bl[(tt + 2) % 3], tt + 2);   // post-barrier: race-free
        compute(tt % 3, (tt & 1) ? aB : aA);
    }

    // epilogue: m = max over this block's cols of sb[col]*dot; atomicMax per row.
    // sa[row] is a positive per-row constant -> applied in k_final (max commutes).
    const int rowbase = mt * BM + wm;
    const int colbase = nt * BN + wn;
    float sbv[8];
    bool cok[8];
#pragma unroll
    for (int ni = 0; ni < 8; ni++) {
        int col = colbase + ni * 16 + lr;
        cok[ni] = (col < NBANK);
        sbv[ni] = sb[col];
    }
#pragma unroll
    for (int mi = 0; mi < 4; mi++) {
#pragma unroll
        for (int j = 0; j < 4; j++) {
            float m = -3.4e38f;
#pragma unroll
            for (int ni = 0; ni < 8; ni++)
                if (cok[ni]) m = fmaxf(m, sbv[ni] * (float)acc[mi][ni][j]);
#pragma unroll
            for (int d = 1; d < 16; d <<= 1)   // reduce 16 lanes sharing a C-row
                m = fmaxf(m, __shfl_xor(m, d));
            if (lr == 0) {
                int row = rowbase + mi * 16 + khi * 4 + j;
                if (row < NPATCH) atomicMax(&keys[row], fkey(m));
            }
        }
    }
}

// ---- kernel 4: scores[b] = max_j sqrt(max(2 - 2*sa*keymax, 1e-12)) ----
__global__ void k_final(const unsigned* __restrict__ keys, const float* __restrict__ sa,
                        float* __restrict__ out) {
    int b = threadIdx.x;
    if (b >= 64) return;
    float best = 0.f;
    for (int j = 0; j < 49; j++) {
        int row = b * 49 + j;
        float c = sa[row] * funkey(keys[row]);
        float d2 = fmaxf(2.0f - 2.0f * c, 1e-12f);
        best = fmaxf(best, sqrtf(d2));
    }
    out[b] = best;
}

extern "C" void kernel_launch(void* const* d_in, const int* in_sizes, int n_in,
                              void* d_out, int out_size, void* d_ws, size_t ws_size,
                              hipStream_t stream) {
    const float* tokens = (const float*)d_in[0];   // [64, 50, 768] f32
    const float* mb     = (const float*)d_in[1];   // [100000, 768] f32
    float* out = (float*)d_out;                    // [64] f32

    // ws layout (16B-aligned regions):
    //   Aq i8 [MPAD*DIM] | Af i8 [NCHUNK*16] | Bf i8 [KTILES*NBRG*64*16]
    //   | sa f32[MPAD] | sb f32[NBPAD] | keys u32[MPAD]
    char* ws = (char*)d_ws;
    signed char* Aq = (signed char*)ws;
    signed char* Af = (signed char*)(ws + (size_t)MPAD * DIM);
    signed char* Bf = (signed char*)(ws + (size_t)MPAD * DIM + (size_t)NCHUNK * 16);
    float* sa       = (float*)(ws + (size_t)MPAD * DIM + (size_t)NCHUNK * 16
                                  + (size_t)KTILES * NBRG * 64 * 16);
    float* sb       = sa + MPAD;
    unsigned* keys  = (unsigned*)(sb + NBPAD);

    k_init <<<(MPAD + 255) / 256, 256, 0, stream>>>(keys);
    k_q8a  <<<MPAD / 4, 256, 0, stream>>>(tokens, Aq, sa);
    k_rep  <<<(NCHUNK + 255) / 256, 256, 0, stream>>>(Aq, Af);
    k_q8b  <<<NBRG, 256, 0, stream>>>(mb, Bf, sb);
    k_gemm <<<MT * NT, 256, 0, stream>>>(Af, Bf, sb, keys);
    k_final<<<1, 64, 0, stream>>>(keys, sa, out);
}

// Round 17
// 340.899 us; speedup vs baseline: 1.2162x; 1.0205x over previous
//
#include <hip/hip_runtime.h>
#include <stdint.h>

// ---- problem constants ----
#define NPATCH 3136      // 64 images * 49 patches
#define MPAD   3328      // 26 * 128 (= 208 * 16)
#define NBANK  100000
#define NBPAD  100096    // 6256 * 16 = 391 * 256
#define DIM    768
#define BM 128
#define BN 256
#define BK 64               // K-tile
#define KTILES (DIM / BK)   // 12
#define MT 26               // MPAD / BM
#define NT 391              // NBPAD / BN
#define NRG    (MPAD / 16)   // 208 A row-groups
#define NBRG   (NBPAD / 16)  // 6256 B row-groups
#define NCHUNK (KTILES * NRG * 64)   // 159744 16B chunks in Af

typedef __attribute__((ext_vector_type(4))) float f32x4;
typedef __attribute__((ext_vector_type(4))) int   i32x4;

// monotonic float<->uint mapping for atomicMax on floats (incl. negatives)
__device__ __forceinline__ unsigned fkey(float f) {
    unsigned u = __float_as_uint(f);
    return (u & 0x80000000u) ? ~u : (u | 0x80000000u);
}
__device__ __forceinline__ float funkey(unsigned u) {
    return __uint_as_float((u & 0x80000000u) ? (u ^ 0x80000000u) : ~u);
}

// ---- kernel 0: zero the per-patch max-key buffer ----
__global__ void k_init(unsigned* __restrict__ keys) {
    int i = blockIdx.x * 256 + threadIdx.x;
    if (i < MPAD) keys[i] = 0u;
}

// ---- shared: quantize one 768-float row to int8 with scale sa = vmax/(127*(||a||+eps))
// dst may be global or LDS (generic address space).
__device__ __forceinline__ void quant_row(const float* __restrict__ src,
                                          signed char* __restrict__ dst,
                                          float* __restrict__ sa_p, int lane) {
    f32x4 v[3];
    float ss = 0.f, vm = 0.f;
#pragma unroll
    for (int i = 0; i < 3; i++) {
        v[i] = ((const f32x4*)src)[lane + 64 * i];
#pragma unroll
        for (int c = 0; c < 4; c++) {
            ss += v[i][c] * v[i][c];
            vm = fmaxf(vm, fabsf(v[i][c]));
        }
    }
#pragma unroll
    for (int d = 1; d < 64; d <<= 1) {
        ss += __shfl_xor(ss, d);
        vm = fmaxf(vm, __shfl_xor(vm, d));
    }
    float k = (vm > 0.f) ? 127.0f / vm : 0.f;
#pragma unroll
    for (int i = 0; i < 3; i++) {
        char4 o;
        o.x = (signed char)__float2int_rn(v[i][0] * k);
        o.y = (signed char)__float2int_rn(v[i][1] * k);
        o.z = (signed char)__float2int_rn(v[i][2] * k);
        o.w = (signed char)__float2int_rn(v[i][3] * k);
        ((char4*)dst)[lane + 64 * i] = o;
    }
    if (lane == 0) *sa_p = vm / (127.0f * (sqrtf(ss) + 1e-12f));
}

__device__ __forceinline__ void zero_row(signed char* __restrict__ dst,
                                         float* __restrict__ sa_p, int lane) {
    char4 z; z.x = z.y = z.z = z.w = 0;
#pragma unroll
    for (int i = 0; i < 3; i++) ((char4*)dst)[lane + 64 * i] = z;
    if (lane == 0) *sa_p = 0.f;
}

// ---- kernel 1: patches (drop CLS) -> int8 Aq[MPAD][DIM] + sa[MPAD] ----
__global__ void k_q8a(const float* __restrict__ tokens, signed char* __restrict__ A,
                      float* __restrict__ sa) {
    int wv = threadIdx.x >> 6, lane = threadIdx.x & 63;
    int r = blockIdx.x * 4 + wv;
    if (r >= MPAD) return;
    signed char* dst = A + (size_t)r * DIM;
    if (r >= NPATCH) { zero_row(dst, sa + r, lane); return; }
    int b = r / 49, j = r % 49;
    const float* src = tokens + (size_t)(b * 50 + 1 + j) * DIM;  // skip CLS
    quant_row(src, dst, sa + r, lane);
}

// ---- kernel 1b: repack Aq row-major -> Af fragment-major (R9-proven).
// Af chunk d = ((kt*NRG + rg)*64 + khi*16 + lr) holds Aq[rg*16+lr][kt*64+khi*16 .. +16).
__global__ void k_rep(const signed char* __restrict__ Aq, signed char* __restrict__ Af) {
    int d = blockIdx.x * 256 + threadIdx.x;
    if (d >= NCHUNK) return;
    int l6 = d & 63;
    int rg = (d >> 6) % NRG;
    int kt = d / (NRG * 64);
    int row = rg * 16 + (l6 & 15);
    int kc  = kt * 64 + (l6 >> 4) * 16;
    *(i32x4*)(Af + (size_t)d * 16) = *(const i32x4*)(Aq + (size_t)row * DIM + kc);
}

// ---- kernel 2: bank -> int8 fragment-major Bf + sb, fused quant+transpose.
// One block per 16-row group: quant rows into LDS (padded stride), then write out
// 12 kt-chunks of 1 KB each, fully coalesced. Bf mirrors Af with NBRG groups.
__global__ void __launch_bounds__(256) k_q8b(const float* __restrict__ mb,
                                             signed char* __restrict__ Bf,
                                             float* __restrict__ sb) {
    __shared__ __align__(16) signed char sm[16][784];   // 784 = 768+16 (bank-spread pad)
    int rg = blockIdx.x;                                 // 0..NBRG-1
    int wv = threadIdx.x >> 6, lane = threadIdx.x & 63;
#pragma unroll
    for (int j = 0; j < 4; j++) {
        int ri = wv * 4 + j;
        int row = rg * 16 + ri;
        if (row < NBANK) quant_row(mb + (size_t)row * DIM, &sm[ri][0], sb + row, lane);
        else             zero_row(&sm[ri][0], sb + row, lane);
    }
    __syncthreads();
    int t = threadIdx.x;
#pragma unroll
    for (int i = 0; i < 3; i++) {
        int idx = i * 256 + t;          // 0..767 = kt(12) * 64 lane-chunks
        int kt = idx >> 6, l6 = idx & 63;
        i32x4 v = *(const i32x4*)(&sm[l6 & 15][kt * 64 + (l6 >> 4) * 16]);
        *(i32x4*)(Bf + (((size_t)kt * NBRG + rg) * 64 + l6) * 16) = v;
    }
}

// ---- kernel 3: int8 MFMA GEMM (16x16x64). R14 free-running structure
// (128x256 block, 4 waves of 64x128, NO per-tile sync) with ONE change:
// A comes from a block-shared LDS half-panel (48 KB = 6 K-tiles), staged by
// global_load_lds twice per kernel (3 __syncthreads total, not per-tile).
// This removes A's 2x-redundant per-wave global loads: TA bytes/block/tile
// 48 KB -> 40 KB (the confirmed ~36 B/cyc/CU vector-memory wall, R11->R14).
// B stays register-double-buffered direct-from-global (R14-proven).
__global__ void __launch_bounds__(256, 2) k_gemm(const signed char* __restrict__ Af,
                                                 const signed char* __restrict__ Bf,
                                                 const float* __restrict__ sb,
                                                 unsigned* __restrict__ keys) {
    __shared__ __align__(16) signed char Al[6 * 8192];   // 48 KB: 6 K-tiles x 8 KB

    // T1: bijective XCD swizzle (m204; nwg=10166, nwg%8=6)
    const int nwg = MT * NT;
    const int q = nwg >> 3, r8 = nwg & 7;
    const int xcd = blockIdx.x & 7, loc = blockIdx.x >> 3;
    const int wg = (xcd < r8 ? xcd * (q + 1) : r8 * (q + 1) + (xcd - r8) * q) + loc;
    const int mt = wg % MT;          // m-fastest within an XCD: 26 blocks share one B panel
    const int nt = wg / MT;

    const int t = threadIdx.x;
    const int lane = t & 63, wv = t >> 6;
    const int lr = lane & 15;
    const int khi = lane >> 4;         // 0..3 -> 16 B k-chunk of the 64-elem k

    const int wm = (wv >> 1) * 64;     // 0 or 64
    const int wn = (wv & 1) * 128;     // 0 or 128

    const int cg0 = nt * (BN / 16) + (wn >> 4);
    const signed char* Bfw = Bf + ((size_t)cg0 * 64 + lane) * 16;

    // Stage 6 K-tiles of the block's A panel (8 row-groups at mt*8) into LDS.
    // Af is fragment-major: for fixed kt the 8 KB panel is contiguous -> linear
    // copy, linear LDS dest (rule #21 trivially satisfied).
    auto stageA = [&](int ktBase) {
#pragma unroll
        for (int k6 = 0; k6 < 6; k6++) {
            const signed char* src = Af + (((size_t)(ktBase + k6) * NRG + mt * 8) << 10);
#pragma unroll
            for (int it = 0; it < 2; it++) {
                int id = it * 256 + t;
                __builtin_amdgcn_global_load_lds(
                    (const __attribute__((address_space(1))) unsigned int*)(src + id * 16),
                    (__attribute__((address_space(3))) unsigned int*)(Al + k6 * 8192 + id * 16),
                    16, 0, 0);
            }
        }
    };

    auto loadB = [&](i32x4* b, int kt) {
#pragma unroll
        for (int ni = 0; ni < 8; ni++)
            b[ni] = *(const i32x4*)(Bfw + (((size_t)kt * NBRG + ni) << 10));
    };

    i32x4 acc[4][8] = {};
    const int abase = (wv >> 1) * 4096 + lane * 16;   // this wave's A half-panel slot

    auto compute = [&](const i32x4* bv, int ktL) {
        i32x4 av[4];
#pragma unroll
        for (int mi = 0; mi < 4; mi++)                 // linear ds_read_b128, LDS pipe
            av[mi] = *(const i32x4*)(Al + ktL * 8192 + abase + mi * 1024);
        __builtin_amdgcn_s_setprio(1);
#pragma unroll
        for (int mi = 0; mi < 4; mi++)
#pragma unroll
            for (int ni = 0; ni < 8; ni++)
                acc[mi][ni] = __builtin_amdgcn_mfma_i32_16x16x64_i8(
                    av[mi], bv[ni], acc[mi][ni], 0, 0, 0);
        __builtin_amdgcn_s_setprio(0);
    };

    i32x4 bA[8], bB[8];
    stageA(0);                          // K-tiles 0..5 -> LDS
    loadB(bA, 0);
    __syncthreads();                    // drains DMA + loadB(0); panel ready
#pragma unroll
    for (int tt = 0; tt < KTILES; tt++) {
        if (tt == 6) {                  // swap in K-tiles 6..11 (only mid-kernel sync)
            __syncthreads();            // all waves done reading tiles 0..5
            stageA(6);
            __syncthreads();            // all waves' stage landed (vmcnt drain inside)
        }
        if (tt + 1 < KTILES) loadB((tt & 1) ? bA : bB, tt + 1);   // reg prefetch
        compute((tt & 1) ? bB : bA, tt % 6);
    }

    // epilogue: m = max over this block's cols of sb[col]*dot; atomicMax per row.
    // sa[row] is a positive per-row constant -> applied in k_final (max commutes).
    const int rowbase = mt * BM + wm;
    const int colbase = nt * BN + wn;
    float sbv[8];
    bool cok[8];
#pragma unroll
    for (int ni = 0; ni < 8; ni++) {
        int col = colbase + ni * 16 + lr;
        cok[ni] = (col < NBANK);
        sbv[ni] = sb[col];
    }
#pragma unroll
    for (int mi = 0; mi < 4; mi++) {
#pragma unroll
        for (int j = 0; j < 4; j++) {
            float m = -3.4e38f;
#pragma unroll
            for (int ni = 0; ni < 8; ni++)
                if (cok[ni]) m = fmaxf(m, sbv[ni] * (float)acc[mi][ni][j]);
#pragma unroll
            for (int d = 1; d < 16; d <<= 1)   // reduce 16 lanes sharing a C-row
                m = fmaxf(m, __shfl_xor(m, d));
            if (lr == 0) {
                int row = rowbase + mi * 16 + khi * 4 + j;
                if (row < NPATCH) atomicMax(&keys[row], fkey(m));
            }
        }
    }
}

// ---- kernel 4: scores[b] = max_j sqrt(max(2 - 2*sa*keymax, 1e-12)) ----
__global__ void k_final(const unsigned* __restrict__ keys, const float* __restrict__ sa,
                        float* __restrict__ out) {
    int b = threadIdx.x;
    if (b >= 64) return;
    float best = 0.f;
    for (int j = 0; j < 49; j++) {
        int row = b * 49 + j;
        float c = sa[row] * funkey(keys[row]);
        float d2 = fmaxf(2.0f - 2.0f * c, 1e-12f);
        best = fmaxf(best, sqrtf(d2));
    }
    out[b] = best;
}

extern "C" void kernel_launch(void* const* d_in, const int* in_sizes, int n_in,
                              void* d_out, int out_size, void* d_ws, size_t ws_size,
                              hipStream_t stream) {
    const float* tokens = (const float*)d_in[0];   // [64, 50, 768] f32
    const float* mb     = (const float*)d_in[1];   // [100000, 768] f32
    float* out = (float*)d_out;                    // [64] f32

    // ws layout (16B-aligned regions):
    //   Aq i8 [MPAD*DIM] | Af i8 [NCHUNK*16] | Bf i8 [KTILES*NBRG*64*16]
    //   | sa f32[MPAD] | sb f32[NBPAD] | keys u32[MPAD]
    char* ws = (char*)d_ws;
    signed char* Aq = (signed char*)ws;
    signed char* Af = (signed char*)(ws + (size_t)MPAD * DIM);
    signed char* Bf = (signed char*)(ws + (size_t)MPAD * DIM + (size_t)NCHUNK * 16);
    float* sa       = (float*)(ws + (size_t)MPAD * DIM + (size_t)NCHUNK * 16
                                  + (size_t)KTILES * NBRG * 64 * 16);
    float* sb       = sa + MPAD;
    unsigned* keys  = (unsigned*)(sb + NBPAD);

    k_init <<<(MPAD + 255) / 256, 256, 0, stream>>>(keys);
    k_q8a  <<<MPAD / 4, 256, 0, stream>>>(tokens, Aq, sa);
    k_rep  <<<(NCHUNK + 255) / 256, 256, 0, stream>>>(Aq, Af);
    k_q8b  <<<NBRG, 256, 0, stream>>>(mb, Bf, sb);
    k_gemm <<<MT * NT, 256, 0, stream>>>(Af, Bf, sb, keys);
    k_final<<<1, 64, 0, stream>>>(keys, sa, out);
}